// Round 1
// baseline (315.943 us; speedup 1.0000x reference)
//
#include <hip/hip_runtime.h>

#define M_ROWS 16384
#define KD 2048
#define NQ 256
#define NE 64
#define INV_SQRT_DQ 0.0625f
#define NOISE_STD_C 0.1f

typedef _Float16 f16x8 __attribute__((ext_vector_type(8)));
typedef float f32x4 __attribute__((ext_vector_type(4)));

__device__ inline void split8(const float4& a, const float4& b, f16x8* h, f16x8* l) {
    float v[8] = {a.x, a.y, a.z, a.w, b.x, b.y, b.z, b.w};
    f16x8 hh, ll;
#pragma unroll
    for (int i = 0; i < 8; ++i) {
        _Float16 s = (_Float16)v[i];
        hh[i] = s;
        ll[i] = (_Float16)(v[i] - (float)s);
    }
    *h = hh;
    *l = ll;
}

// ---------------------------------------------------------------------------
// Kernel 1: transpose + hi/lo split of w_q [2048][256] -> w_t_hi/lo [256][2048] f16
// grid (32, 4), 256 threads
__global__ void prep_w(const float* __restrict__ w, _Float16* __restrict__ wh,
                       _Float16* __restrict__ wl) {
    __shared__ float tile[64][65];
    const int k0 = blockIdx.x * 64;
    const int n0 = blockIdx.y * 64;
    const int t = threadIdx.x;

    const int r = t >> 2;          // k-row 0..63
    const int c4 = (t & 3) * 4;    // col phase
#pragma unroll
    for (int i = 0; i < 4; ++i) {
        int c = c4 + 16 * i;
        const float4 v = *(const float4*)(w + (size_t)(k0 + r) * NQ + n0 + c);
        tile[r][c + 0] = v.x; tile[r][c + 1] = v.y;
        tile[r][c + 2] = v.z; tile[r][c + 3] = v.w;
    }
    __syncthreads();

    const int nl = t >> 2;         // local n 0..63
    const int ks = (t & 3) * 16;   // k offset 0,16,32,48
    f16x8 h0, h1, l0, l1;
#pragma unroll
    for (int i = 0; i < 8; ++i) {
        float xv = tile[ks + i][nl];
        _Float16 s = (_Float16)xv;
        h0[i] = s; l0[i] = (_Float16)(xv - (float)s);
    }
#pragma unroll
    for (int i = 0; i < 8; ++i) {
        float xv = tile[ks + 8 + i][nl];
        _Float16 s = (_Float16)xv;
        h1[i] = s; l1[i] = (_Float16)(xv - (float)s);
    }
    size_t base = (size_t)(n0 + nl) * KD + (k0 + ks);
    *(f16x8*)(wh + base) = h0;
    *(f16x8*)(wh + base + 8) = h1;
    *(f16x8*)(wl + base) = l0;
    *(f16x8*)(wl + base + 8) = l1;
}

// ---------------------------------------------------------------------------
// Kernel 2: query = x @ w_q + b_q  via 3-pass f16-split MFMA.
// BM=64, BN=256 (full), BK=32. grid 256, 256 threads (4 waves, wave = n-quarter).
#define BM 64
#define BK 32
#define APITCH 40   // f16 pitch: 80B rows, 16B-aligned, 2-way-free banks

__global__ __launch_bounds__(256, 1) void gemm_q(
    const float* __restrict__ x, const _Float16* __restrict__ wh,
    const _Float16* __restrict__ wl, const float* __restrict__ bq,
    float* __restrict__ q) {
    __shared__ _Float16 Ah[BM][APITCH];
    __shared__ _Float16 Al[BM][APITCH];

    const int t = threadIdx.x;
    const int lane = t & 63;
    const int wv = t >> 6;               // wave 0..3 -> n range [64*wv, 64*wv+64)
    const int m0 = blockIdx.x * BM;

    // staging: thread covers (row sr, k [sk, sk+8))
    const int sr = t >> 2;
    const int sk = (t & 3) * 8;
    const float* xrow = x + (size_t)(m0 + sr) * KD + sk;

    // fragment indexing
    const int fm = lane & 15;
    const int kq = (lane >> 4) * 8;

    f32x4 acc[4][4];
#pragma unroll
    for (int mt = 0; mt < 4; ++mt)
#pragma unroll
        for (int nt = 0; nt < 4; ++nt)
            acc[mt][nt] = {0.f, 0.f, 0.f, 0.f};

    const _Float16* bhp[4];
    const _Float16* blp[4];
#pragma unroll
    for (int nt = 0; nt < 4; ++nt) {
        int n = 64 * wv + nt * 16 + fm;
        bhp[nt] = wh + (size_t)n * KD + kq;
        blp[nt] = wl + (size_t)n * KD + kq;
    }

    // prefetch x chunk 0
    float4 xa = *(const float4*)(xrow + 0);
    float4 xb = *(const float4*)(xrow + 4);

    for (int kc = 0; kc < KD; kc += BK) {
        __syncthreads();  // previous compute done; safe to overwrite tile
        f16x8 h8, l8;
        split8(xa, xb, &h8, &l8);
        *(f16x8*)&Ah[sr][sk] = h8;
        *(f16x8*)&Al[sr][sk] = l8;
        if (kc + BK < KD) {  // prefetch next x chunk
            xa = *(const float4*)(xrow + kc + BK);
            xb = *(const float4*)(xrow + kc + BK + 4);
        }
        // B fragments straight from L2-resident pre-split w_t
        f16x8 bh[4], bl[4];
#pragma unroll
        for (int nt = 0; nt < 4; ++nt) {
            bh[nt] = *(const f16x8*)(bhp[nt] + kc);
            bl[nt] = *(const f16x8*)(blp[nt] + kc);
        }
        __syncthreads();  // tile ready
        f16x8 ah[4], al[4];
#pragma unroll
        for (int mt = 0; mt < 4; ++mt) {
            ah[mt] = *(const f16x8*)&Ah[mt * 16 + fm][kq];
            al[mt] = *(const f16x8*)&Al[mt * 16 + fm][kq];
        }
#pragma unroll
        for (int mt = 0; mt < 4; ++mt)
#pragma unroll
            for (int nt = 0; nt < 4; ++nt) {
                acc[mt][nt] = __builtin_amdgcn_mfma_f32_16x16x32_f16(ah[mt], bh[nt], acc[mt][nt], 0, 0, 0);
                acc[mt][nt] = __builtin_amdgcn_mfma_f32_16x16x32_f16(ah[mt], bl[nt], acc[mt][nt], 0, 0, 0);
                acc[mt][nt] = __builtin_amdgcn_mfma_f32_16x16x32_f16(al[mt], bh[nt], acc[mt][nt], 0, 0, 0);
            }
    }

    // epilogue: +bias, store query (C/D layout: col=lane&15, row=(lane>>4)*4+r)
#pragma unroll
    for (int nt = 0; nt < 4; ++nt) {
        int col = 64 * wv + nt * 16 + fm;
        float bias = bq[col];
#pragma unroll
        for (int mt = 0; mt < 4; ++mt) {
#pragma unroll
            for (int r = 0; r < 4; ++r) {
                int row = m0 + mt * 16 + (lane >> 4) * 4 + r;
                q[(size_t)row * NQ + col] = acc[mt][nt][r] + bias;
            }
        }
    }
}

// ---------------------------------------------------------------------------
// Kernel 3: logits = q@keys^T/16 + noise*0.1; top-2; softmax; scatter.
// grid 256 (64 rows each), 256 threads (4 waves; wave = 16-expert slice).
__global__ __launch_bounds__(256, 1) void logits_topk(
    const float* __restrict__ q, const float* __restrict__ keys,
    const float* __restrict__ noise, float* __restrict__ gate,
    float* __restrict__ idxout) {
    __shared__ float LG[64][65];
    const int t = threadIdx.x;
    const int lane = t & 63;
    const int wv = t >> 6;
    const int m0 = blockIdx.x * 64;
    const int fm = lane & 15;
    const int kq = (lane >> 4) * 8;
    const int e = wv * 16 + fm;

    f32x4 acc[4];
#pragma unroll
    for (int mt = 0; mt < 4; ++mt) acc[mt] = {0.f, 0.f, 0.f, 0.f};

    const float* kp = keys + (size_t)e * NQ + kq;
    for (int kc = 0; kc < NQ; kc += 32) {
        float4 b0 = *(const float4*)(kp + kc);
        float4 b1 = *(const float4*)(kp + kc + 4);
        f16x8 bh, bl;
        split8(b0, b1, &bh, &bl);
#pragma unroll
        for (int mt = 0; mt < 4; ++mt) {
            const float* ap = q + (size_t)(m0 + mt * 16 + fm) * NQ + kc + kq;
            float4 a0 = *(const float4*)ap;
            float4 a1 = *(const float4*)(ap + 4);
            f16x8 ah, al;
            split8(a0, a1, &ah, &al);
            acc[mt] = __builtin_amdgcn_mfma_f32_16x16x32_f16(ah, bh, acc[mt], 0, 0, 0);
            acc[mt] = __builtin_amdgcn_mfma_f32_16x16x32_f16(ah, bl, acc[mt], 0, 0, 0);
            acc[mt] = __builtin_amdgcn_mfma_f32_16x16x32_f16(al, bh, acc[mt], 0, 0, 0);
        }
    }
    // scale + noise, park in LDS for cross-wave top-k
#pragma unroll
    for (int mt = 0; mt < 4; ++mt) {
#pragma unroll
        for (int r = 0; r < 4; ++r) {
            int row = mt * 16 + (lane >> 4) * 4 + r;
            float lg = acc[mt][r] * INV_SQRT_DQ +
                       NOISE_STD_C * noise[(size_t)(m0 + row) * NE + e];
            LG[row][e] = lg;
        }
    }
    __syncthreads();

    // top-2 per row; wave wv handles rows [16*wv, 16*wv+16); lane = expert
    for (int i = 0; i < 16; ++i) {
        int r = wv * 16 + i;
        float v = LG[r][lane];
        // argmax with jax tie-break (equal -> lower index)
        float v1 = v; int i1 = lane;
#pragma unroll
        for (int off = 32; off; off >>= 1) {
            float ov = __shfl_xor(v1, off);
            int oi = __shfl_xor(i1, off);
            if (ov > v1 || (ov == v1 && oi < i1)) { v1 = ov; i1 = oi; }
        }
        float v2 = (lane == i1) ? -1e30f : v;
        int i2 = lane;
#pragma unroll
        for (int off = 32; off; off >>= 1) {
            float ov = __shfl_xor(v2, off);
            int oi = __shfl_xor(i2, off);
            if (ov > v2 || (ov == v2 && oi < i2)) { v2 = ov; i2 = oi; }
        }
        float ex = expf(v2 - v1);           // v2 <= v1, stable
        float p1 = 1.0f / (1.0f + ex);
        float p2 = ex * p1;
        float g = (lane == i1) ? p1 : ((lane == i2) ? p2 : 0.0f);
        gate[(size_t)(m0 + r) * NE + lane] = g;
        if (lane == 0) {
            float2 ii = make_float2((float)i1, (float)i2);
            *(float2*)(idxout + (size_t)(m0 + r) * 2) = ii;
        }
    }
}

// ---------------------------------------------------------------------------
extern "C" void kernel_launch(void* const* d_in, const int* in_sizes, int n_in,
                              void* d_out, int out_size, void* d_ws, size_t ws_size,
                              hipStream_t stream) {
    const float* x     = (const float*)d_in[0];
    const float* noise = (const float*)d_in[1];
    const float* w_q   = (const float*)d_in[2];
    const float* b_q   = (const float*)d_in[3];
    const float* keys  = (const float*)d_in[4];
    float* out = (float*)d_out;

    char* ws = (char*)d_ws;
    _Float16* wh = (_Float16*)ws;                      // 1 MB
    _Float16* wl = (_Float16*)(ws + (1u << 20));       // 1 MB
    float* q     = (float*)(ws + (2u << 20));          // 16 MB

    prep_w<<<dim3(32, 4), 256, 0, stream>>>(w_q, wh, wl);
    gemm_q<<<dim3(256), 256, 0, stream>>>(x, wh, wl, b_q, q);
    logits_topk<<<dim3(256), 256, 0, stream>>>(q, keys, noise, out, out + (size_t)M_ROWS * NE);
}

// Round 2
// 258.969 us; speedup vs baseline: 1.2200x; 1.2200x over previous
//
#include <hip/hip_runtime.h>

#define MROWS 16384
#define KD 2048
#define NQ 256
#define NE 64
#define INV_SQRT_DQ 0.0625f
#define NOISE_STD_C 0.1f

typedef _Float16 f16x8 __attribute__((ext_vector_type(8)));
typedef float f32x4 __attribute__((ext_vector_type(4)));

__device__ inline void split8(const float4& a, const float4& b, f16x8* h, f16x8* l) {
    float v[8] = {a.x, a.y, a.z, a.w, b.x, b.y, b.z, b.w};
    f16x8 hh, ll;
#pragma unroll
    for (int i = 0; i < 8; ++i) {
        _Float16 s = (_Float16)v[i];
        hh[i] = s;
        ll[i] = (_Float16)(v[i] - (float)s);
    }
    *h = hh;
    *l = ll;
}

// ---------------------------------------------------------------------------
// Kernel 1: w_q [2048][256] f32 -> B-fragment-packed hi/lo f16 arrays.
// Packed layout: off(n,k) = (((k>>5)*16 + (n>>4))*64 + ((k>>3)&3)*16 + (n&15))*8 + (k&7)
// so a wave's 16B/lane B-frag load for (kc, ngrp) is one contiguous 1KB burst.
// 65536 octets, grid 256 x 256.
__global__ void prep_w(const float* __restrict__ w, _Float16* __restrict__ whp,
                       _Float16* __restrict__ wlp) {
    const int tid = blockIdx.x * 256 + threadIdx.x;
    const int f    = tid & 15;
    const int q    = (tid >> 4) & 3;
    const int ngrp = (tid >> 6) & 15;
    const int kcs  = tid >> 10;
    const int n = ngrp * 16 + f;
    const int k = kcs * 32 + q * 8;
    f16x8 h, l;
#pragma unroll
    for (int j = 0; j < 8; ++j) {
        float v = w[(size_t)(k + j) * NQ + n];
        _Float16 s = (_Float16)v;
        h[j] = s;
        l[j] = (_Float16)(v - (float)s);
    }
    *(f16x8*)(whp + (size_t)tid * 8) = h;
    *(f16x8*)(wlp + (size_t)tid * 8) = l;
}

// ---------------------------------------------------------------------------
// Kernel 2 (fused): query GEMM (3-pass f16-split MFMA) + logits + top-2 +
// softmax + scatter. BM=64, BN=256, BK=64. grid 256, 512 threads (8 waves,
// wave = 32-col n-slice). q never leaves LDS.
__global__ __launch_bounds__(512) void gemm_fused(
    const float* __restrict__ x, const _Float16* __restrict__ whp,
    const _Float16* __restrict__ wlp, const float* __restrict__ bq,
    const float* __restrict__ keys, const float* __restrict__ noise,
    float* __restrict__ gate, float* __restrict__ idxout) {
    // LDS: Ah[64][64] (8KB) + Al[64][64] (8KB); LG[64][65] (16.6KB) overlaps both;
    // qs[64][268] f32 (68.6KB) after. Total 85248 B.
    __shared__ __align__(16) char smem[85248];
    _Float16* Ah = (_Float16*)smem;
    _Float16* Al = (_Float16*)(smem + 8192);
    float* LG = (float*)smem;
    float* qs = (float*)(smem + 16640);

    const int t = threadIdx.x;
    const int lane = t & 63;
    const int wv = t >> 6;             // 0..7, n-slice [32*wv, 32*wv+32)
    const int m0 = blockIdx.x * 64;
    const int f = lane & 15;
    const int qq = lane >> 4;          // 0..3

    // staging: thread -> (row srow, k-octet sk8), swizzled LDS col
    const int srow = t >> 3;
    const int sk8 = (t & 7) * 8;
    const int scol = sk8 ^ ((srow & 7) * 8);
    const float* xp = x + (size_t)(m0 + srow) * KD + sk8;

    f32x4 acc[4][2];
#pragma unroll
    for (int mt = 0; mt < 4; ++mt)
#pragma unroll
        for (int nt = 0; nt < 2; ++nt) acc[mt][nt] = {0.f, 0.f, 0.f, 0.f};

    // prefetch tile 0 (8 floats/thread)
    float4 pfA = *(const float4*)xp;
    float4 pfB = *(const float4*)(xp + 4);

    const int aswz = (f & 7) * 8;

    for (int i = 0; i < 32; ++i) {
        __syncthreads();  // previous tile fully consumed
        f16x8 h8, l8;
        split8(pfA, pfB, &h8, &l8);
        *(f16x8*)(Ah + srow * 64 + scol) = h8;
        *(f16x8*)(Al + srow * 64 + scol) = l8;
        __syncthreads();  // tile ready
        // all global loads issued AFTER the barrier: nothing in flight at a barrier
        if (i < 31) {
            pfA = *(const float4*)(xp + (i + 1) * 64);
            pfB = *(const float4*)(xp + (i + 1) * 64 + 4);
        }
        f16x8 bh[2][2], bl[2][2];
#pragma unroll
        for (int ks = 0; ks < 2; ++ks)
#pragma unroll
            for (int nt = 0; nt < 2; ++nt) {
                size_t o = ((size_t)((2 * i + ks) * 16 + 2 * wv + nt) * 64 + lane) * 8;
                bh[ks][nt] = *(const f16x8*)(whp + o);
                bl[ks][nt] = *(const f16x8*)(wlp + o);
            }
#pragma unroll
        for (int ks = 0; ks < 2; ++ks) {
            f16x8 ah[4], al[4];
#pragma unroll
            for (int mt = 0; mt < 4; ++mt) {
                int ab = (mt * 16 + f) * 64 + ((ks * 32 + qq * 8) ^ aswz);
                ah[mt] = *(const f16x8*)(Ah + ab);
                al[mt] = *(const f16x8*)(Al + ab);
            }
#pragma unroll
            for (int mt = 0; mt < 4; ++mt)
#pragma unroll
                for (int nt = 0; nt < 2; ++nt) {
                    acc[mt][nt] = __builtin_amdgcn_mfma_f32_16x16x32_f16(ah[mt], bh[ks][nt], acc[mt][nt], 0, 0, 0);
                    acc[mt][nt] = __builtin_amdgcn_mfma_f32_16x16x32_f16(ah[mt], bl[ks][nt], acc[mt][nt], 0, 0, 0);
                    acc[mt][nt] = __builtin_amdgcn_mfma_f32_16x16x32_f16(al[mt], bh[ks][nt], acc[mt][nt], 0, 0, 0);
                }
        }
    }

    // epilogue: +bias, park q tile (f32) in LDS
#pragma unroll
    for (int nt = 0; nt < 2; ++nt) {
        int col = wv * 32 + nt * 16 + f;
        float bias = bq[col];
#pragma unroll
        for (int mt = 0; mt < 4; ++mt)
#pragma unroll
            for (int r = 0; r < 4; ++r)
                qs[(mt * 16 + qq * 4 + r) * 268 + col] = acc[mt][nt][r] + bias;
    }
    __syncthreads();

    // logits: waves 0..3 compute 64 rows x 16 experts each (LG overlaps Ah/Al)
    if (wv < 4) {
        f32x4 a2[4];
#pragma unroll
        for (int mt = 0; mt < 4; ++mt) a2[mt] = {0.f, 0.f, 0.f, 0.f};
        const int e = wv * 16 + f;
        const float* kp = keys + (size_t)e * NQ + qq * 8;
        for (int kc = 0; kc < NQ; kc += 32) {
            float4 b0 = *(const float4*)(kp + kc);
            float4 b1 = *(const float4*)(kp + kc + 4);
            f16x8 bh2, bl2;
            split8(b0, b1, &bh2, &bl2);
#pragma unroll
            for (int mt = 0; mt < 4; ++mt) {
                const float* ap = qs + (mt * 16 + f) * 268 + kc + qq * 8;
                float4 a0 = *(const float4*)ap;
                float4 a1 = *(const float4*)(ap + 4);
                f16x8 ah2, al2;
                split8(a0, a1, &ah2, &al2);
                a2[mt] = __builtin_amdgcn_mfma_f32_16x16x32_f16(ah2, bh2, a2[mt], 0, 0, 0);
                a2[mt] = __builtin_amdgcn_mfma_f32_16x16x32_f16(ah2, bl2, a2[mt], 0, 0, 0);
                a2[mt] = __builtin_amdgcn_mfma_f32_16x16x32_f16(al2, bh2, a2[mt], 0, 0, 0);
            }
        }
#pragma unroll
        for (int mt = 0; mt < 4; ++mt)
#pragma unroll
            for (int r = 0; r < 4; ++r) {
                int row = mt * 16 + qq * 4 + r;
                LG[row * 65 + e] = a2[mt][r] * INV_SQRT_DQ +
                                   NOISE_STD_C * noise[(size_t)(m0 + row) * NE + e];
            }
    }
    __syncthreads();

    // top-2 + softmax + scatter: 8 waves x 8 rows, lane = expert
    for (int i = 0; i < 8; ++i) {
        int r = wv * 8 + i;
        float v = LG[r * 65 + lane];
        float v1 = v; int i1 = lane;
#pragma unroll
        for (int off = 32; off; off >>= 1) {
            float ov = __shfl_xor(v1, off);
            int oi = __shfl_xor(i1, off);
            if (ov > v1 || (ov == v1 && oi < i1)) { v1 = ov; i1 = oi; }
        }
        float v2 = (lane == i1) ? -1e30f : v;
        int i2 = lane;
#pragma unroll
        for (int off = 32; off; off >>= 1) {
            float ov = __shfl_xor(v2, off);
            int oi = __shfl_xor(i2, off);
            if (ov > v2 || (ov == v2 && oi < i2)) { v2 = ov; i2 = oi; }
        }
        float ex = expf(v2 - v1);           // v2 <= v1, stable
        float p1 = 1.0f / (1.0f + ex);
        float p2 = ex * p1;
        float g = (lane == i1) ? p1 : ((lane == i2) ? p2 : 0.0f);
        gate[(size_t)(m0 + r) * NE + lane] = g;
        if (lane == 0) {
            float2 ii = make_float2((float)i1, (float)i2);
            *(float2*)(idxout + (size_t)(m0 + r) * 2) = ii;
        }
    }
}

// ---------------------------------------------------------------------------
extern "C" void kernel_launch(void* const* d_in, const int* in_sizes, int n_in,
                              void* d_out, int out_size, void* d_ws, size_t ws_size,
                              hipStream_t stream) {
    const float* x     = (const float*)d_in[0];
    const float* noise = (const float*)d_in[1];
    const float* w_q   = (const float*)d_in[2];
    const float* b_q   = (const float*)d_in[3];
    const float* keys  = (const float*)d_in[4];
    float* out = (float*)d_out;

    char* ws = (char*)d_ws;
    _Float16* whp = (_Float16*)ws;                 // 1 MB, frag-packed hi
    _Float16* wlp = (_Float16*)(ws + (1u << 20));  // 1 MB, frag-packed lo

    prep_w<<<256, 256, 0, stream>>>(w_q, whp, wlp);
    gemm_fused<<<256, 512, 0, stream>>>(x, whp, wlp, b_q, keys, noise,
                                        out, out + (size_t)MROWS * NE);
}

// Round 3
// 231.556 us; speedup vs baseline: 1.3644x; 1.1184x over previous
//
#include <hip/hip_runtime.h>

#define MROWS 16384
#define KD 2048
#define NQ 256
#define NE 64
#define INV_SQRT_DQ 0.0625f
#define NOISE_STD_C 0.1f

typedef _Float16 f16x8 __attribute__((ext_vector_type(8)));
typedef float f32x4 __attribute__((ext_vector_type(4)));

__device__ inline void split8v(f32x4 a, f32x4 b, f16x8* h, f16x8* l) {
    f16x8 hh, ll;
#pragma unroll
    for (int i = 0; i < 4; ++i) {
        _Float16 s = (_Float16)a[i];
        hh[i] = s; ll[i] = (_Float16)(a[i] - (float)s);
    }
#pragma unroll
    for (int i = 0; i < 4; ++i) {
        _Float16 s = (_Float16)b[i];
        hh[4 + i] = s; ll[4 + i] = (_Float16)(b[i] - (float)s);
    }
    *h = hh; *l = ll;
}

// ---------------------------------------------------------------------------
// Kernel 1: w_q [2048][256] f32 -> B-fragment-packed hi/lo f16 arrays.
// off(n,k) = (((k>>5)*16 + (n>>4))*64 + ((k>>3)&3)*16 + (n&15))*8 + (k&7)
__global__ void prep_w(const float* __restrict__ w, _Float16* __restrict__ whp,
                       _Float16* __restrict__ wlp) {
    const int tid = blockIdx.x * 256 + threadIdx.x;
    const int f    = tid & 15;
    const int q    = (tid >> 4) & 3;
    const int ngrp = (tid >> 6) & 15;
    const int kcs  = tid >> 10;
    const int n = ngrp * 16 + f;
    const int k = kcs * 32 + q * 8;
    f16x8 h, l;
#pragma unroll
    for (int j = 0; j < 8; ++j) {
        float v = w[(size_t)(k + j) * NQ + n];
        _Float16 s = (_Float16)v;
        h[j] = s;
        l[j] = (_Float16)(v - (float)s);
    }
    *(f16x8*)(whp + (size_t)tid * 8) = h;
    *(f16x8*)(wlp + (size_t)tid * 8) = l;
}

// ---------------------------------------------------------------------------
// Kernel 2 (fused): query GEMM (3-pass f16-split MFMA) + logits + top-2 +
// softmax + scatter. BM=64, BN=256, BK=64, ping-pong LDS, 1 raw barrier/iter.
// grid 256, 512 threads (8 waves, wave = 32-col n-slice).
__global__ __launch_bounds__(512) void gemm_fused(
    const float* __restrict__ x, const _Float16* __restrict__ whp,
    const _Float16* __restrict__ wlp, const float* __restrict__ bq,
    const float* __restrict__ keys, const float* __restrict__ noise,
    float* __restrict__ gate, float* __restrict__ idxout) {
    // LDS: ping-pong A buffers [0,32K): {Ah0,Al0,Ah1,Al1} 8KB each.
    // Epilogue: qs f32 [64][260] (66.56KB) aliases everything; LG [64][65] aliases qs base.
    __shared__ __align__(16) char smem[66560];

    const int t = threadIdx.x;
    const int lane = t & 63;
    const int wv = t >> 6;              // 0..7, n-slice [32*wv, 32*wv+32)
    const int m0 = blockIdx.x * 64;
    const int f = lane & 15;
    const int qq = lane >> 4;           // 0..3
    const int aswz = (f & 7) * 8;

    // staging: thread -> (row srow, k-octet sk8), XOR-swizzled LDS chunk
    const int srow = t >> 3;
    const int sk8 = (t & 7) * 8;
    const int scol = sk8 ^ ((srow & 7) * 8);
    const f32x4* xp = (const f32x4*)(x + (size_t)(m0 + srow) * KD + sk8);

    // B pointers (frag-packed): frag(kc16, ngrp) at whp + kc16*8192 + ngrp*512 + lane*8
    const _Float16* bph = whp + (size_t)(2 * wv) * 512 + lane * 8;
    const _Float16* bpl = wlp + (size_t)(2 * wv) * 512 + lane * 8;

    f32x4 acc[4][2];
#pragma unroll
    for (int mt = 0; mt < 4; ++mt)
#pragma unroll
        for (int nt = 0; nt < 2; ++nt) acc[mt][nt] = {0.f, 0.f, 0.f, 0.f};

    f16x8 bhC[2][2], blC[2][2], bhN[2][2], blN[2][2];

    // ---- prologue: tile 0 -> buf0; preload b(0) and x(tile1)
    f32x4 xa = __builtin_nontemporal_load(xp);
    f32x4 xb = __builtin_nontemporal_load(xp + 1);
#pragma unroll
    for (int ks = 0; ks < 2; ++ks)
#pragma unroll
        for (int nt = 0; nt < 2; ++nt) {
            size_t o = (size_t)ks * 8192 + nt * 512;
            bhC[ks][nt] = *(const f16x8*)(bph + o);
            blC[ks][nt] = *(const f16x8*)(bpl + o);
        }
    {
        f16x8 h8, l8;
        split8v(xa, xb, &h8, &l8);
        *(f16x8*)((_Float16*)smem + srow * 64 + scol) = h8;
        *(f16x8*)((_Float16*)(smem + 8192) + srow * 64 + scol) = l8;
    }
    xa = __builtin_nontemporal_load(xp + 16);
    xb = __builtin_nontemporal_load(xp + 17);
    __syncthreads();  // one-time full drain

    // ---- K loop: 32 iterations of BK=64
    for (int i = 0; i < 32; ++i) {
        const int cb = i & 1;
        _Float16* AhC = (_Float16*)(smem + cb * 16384);
        _Float16* AlC = AhC + 4096;
        _Float16* AhN = (_Float16*)(smem + (cb ^ 1) * 16384);
        _Float16* AlN = AhN + 4096;

        // prefetch b(i+1): full iteration of slack over L2 latency
        if (i + 1 < 32) {
            size_t base = (size_t)(2 * (i + 1)) * 8192;
#pragma unroll
            for (int ks = 0; ks < 2; ++ks)
#pragma unroll
                for (int nt = 0; nt < 2; ++nt) {
                    size_t o = base + (size_t)ks * 8192 + nt * 512;
                    bhN[ks][nt] = *(const f16x8*)(bph + o);
                    blN[ks][nt] = *(const f16x8*)(bpl + o);
                }
        }
        // stage tile i+1 into the other buffer (x regs loaded 2 iters ago)
        if (i + 1 < 32) {
            f16x8 h8, l8;
            split8v(xa, xb, &h8, &l8);
            *(f16x8*)(AhN + srow * 64 + scol) = h8;
            *(f16x8*)(AlN + srow * 64 + scol) = l8;
        }
        // prefetch x tile i+2 (non-temporal: don't thrash whp out of L2)
        if (i + 2 < 32) {
            xa = __builtin_nontemporal_load(xp + (i + 2) * 16);
            xb = __builtin_nontemporal_load(xp + (i + 2) * 16 + 1);
        }
        // compute on current buffer
#pragma unroll
        for (int ks = 0; ks < 2; ++ks) {
            f16x8 ah[4], al[4];
#pragma unroll
            for (int mt = 0; mt < 4; ++mt) {
                int ab = (mt * 16 + f) * 64 + ((ks * 32 + qq * 8) ^ aswz);
                ah[mt] = *(const f16x8*)(AhC + ab);
                al[mt] = *(const f16x8*)(AlC + ab);
            }
#pragma unroll
            for (int mt = 0; mt < 4; ++mt)
#pragma unroll
                for (int nt = 0; nt < 2; ++nt) {
                    acc[mt][nt] = __builtin_amdgcn_mfma_f32_16x16x32_f16(ah[mt], bhC[ks][nt], acc[mt][nt], 0, 0, 0);
                    acc[mt][nt] = __builtin_amdgcn_mfma_f32_16x16x32_f16(ah[mt], blC[ks][nt], acc[mt][nt], 0, 0, 0);
                    acc[mt][nt] = __builtin_amdgcn_mfma_f32_16x16x32_f16(al[mt], bhC[ks][nt], acc[mt][nt], 0, 0, 0);
                }
        }
#pragma unroll
        for (int ks = 0; ks < 2; ++ks)
#pragma unroll
            for (int nt = 0; nt < 2; ++nt) {
                bhC[ks][nt] = bhN[ks][nt];
                blC[ks][nt] = blN[ks][nt];
            }
        // raw barrier: publish LDS writes (lgkmcnt(0)) WITHOUT draining vmcnt,
        // so b(i+1)/x(i+2) prefetches stay in flight across the barrier.
        asm volatile("" ::: "memory");
        __builtin_amdgcn_s_waitcnt(0xC07F);  // lgkmcnt(0) only
        __builtin_amdgcn_s_barrier();
        asm volatile("" ::: "memory");
    }

    // ---- epilogue: +bias, park q tile in LDS (aliases A buffers; barrier 31 covers)
    float* qs = (float*)smem;  // [64][260]
#pragma unroll
    for (int nt = 0; nt < 2; ++nt) {
        int col = wv * 32 + nt * 16 + f;
        float bias = bq[col];
#pragma unroll
        for (int mt = 0; mt < 4; ++mt)
#pragma unroll
            for (int r = 0; r < 4; ++r)
                qs[(mt * 16 + qq * 4 + r) * 260 + col] = acc[mt][nt][r] + bias;
    }
    __syncthreads();

    // ---- logits: waves 0..3, wave covers 16 experts x 64 rows
    const int e = wv * 16 + f;
    f32x4 a2[4];
#pragma unroll
    for (int mt = 0; mt < 4; ++mt) a2[mt] = {0.f, 0.f, 0.f, 0.f};
    if (wv < 4) {
        const float* kp = keys + (size_t)e * NQ + qq * 8;
        for (int kc = 0; kc < NQ; kc += 32) {
            f32x4 b0 = *(const f32x4*)(kp + kc);
            f32x4 b1 = *(const f32x4*)(kp + kc + 4);
            f16x8 bh2, bl2;
            split8v(b0, b1, &bh2, &bl2);
#pragma unroll
            for (int mt = 0; mt < 4; ++mt) {
                const float* ap = qs + (mt * 16 + f) * 260 + kc + qq * 8;
                f32x4 a0 = *(const f32x4*)ap;
                f32x4 a1 = *(const f32x4*)(ap + 4);
                f16x8 ah2, al2;
                split8v(a0, a1, &ah2, &al2);
                a2[mt] = __builtin_amdgcn_mfma_f32_16x16x32_f16(ah2, bh2, a2[mt], 0, 0, 0);
                a2[mt] = __builtin_amdgcn_mfma_f32_16x16x32_f16(ah2, bl2, a2[mt], 0, 0, 0);
                a2[mt] = __builtin_amdgcn_mfma_f32_16x16x32_f16(al2, bh2, a2[mt], 0, 0, 0);
            }
        }
    }
    __syncthreads();  // all qs reads done before LG (aliases qs base) is written

    float* LG = (float*)smem;  // [64][65]
    if (wv < 4) {
#pragma unroll
        for (int mt = 0; mt < 4; ++mt)
#pragma unroll
            for (int r = 0; r < 4; ++r) {
                int row = mt * 16 + qq * 4 + r;
                LG[row * 65 + e] = a2[mt][r] * INV_SQRT_DQ +
                                   NOISE_STD_C * noise[(size_t)(m0 + row) * NE + e];
            }
    }
    __syncthreads();

    // ---- top-2 + softmax + scatter: 8 waves x 8 rows, lane = expert
    for (int i = 0; i < 8; ++i) {
        int r = wv * 8 + i;
        float v = LG[r * 65 + lane];
        float v1 = v; int i1 = lane;
#pragma unroll
        for (int off = 32; off; off >>= 1) {
            float ov = __shfl_xor(v1, off);
            int oi = __shfl_xor(i1, off);
            if (ov > v1 || (ov == v1 && oi < i1)) { v1 = ov; i1 = oi; }
        }
        float v2 = (lane == i1) ? -1e30f : v;
        int i2 = lane;
#pragma unroll
        for (int off = 32; off; off >>= 1) {
            float ov = __shfl_xor(v2, off);
            int oi = __shfl_xor(i2, off);
            if (ov > v2 || (ov == v2 && oi < i2)) { v2 = ov; i2 = oi; }
        }
        float ex = expf(v2 - v1);           // v2 <= v1, stable
        float p1 = 1.0f / (1.0f + ex);
        float p2 = ex * p1;
        float g = (lane == i1) ? p1 : ((lane == i2) ? p2 : 0.0f);
        gate[(size_t)(m0 + r) * NE + lane] = g;
        if (lane == 0) {
            float2 ii = make_float2((float)i1, (float)i2);
            *(float2*)(idxout + (size_t)(m0 + r) * 2) = ii;
        }
    }
}

// ---------------------------------------------------------------------------
extern "C" void kernel_launch(void* const* d_in, const int* in_sizes, int n_in,
                              void* d_out, int out_size, void* d_ws, size_t ws_size,
                              hipStream_t stream) {
    const float* x     = (const float*)d_in[0];
    const float* noise = (const float*)d_in[1];
    const float* w_q   = (const float*)d_in[2];
    const float* b_q   = (const float*)d_in[3];
    const float* keys  = (const float*)d_in[4];
    float* out = (float*)d_out;

    char* ws = (char*)d_ws;
    _Float16* whp = (_Float16*)ws;                 // 1 MB, frag-packed hi
    _Float16* wlp = (_Float16*)(ws + (1u << 20));  // 1 MB, frag-packed lo

    prep_w<<<256, 256, 0, stream>>>(w_q, whp, wlp);
    gemm_fused<<<256, 512, 0, stream>>>(x, whp, wlp, b_q, keys, noise,
                                        out, out + (size_t)MROWS * NE);
}